// Round 15
// baseline (187.957 us; speedup 1.0000x reference)
//
#include <hip/hip_runtime.h>
#include <cstdint>
#include <cstddef>

// Problem constants
#define NP      2048        // patches
#define NN      100000      // memory nodes
#define DIM     256
#define NT      6250        // 16-node tiles (NN/16)
#define NG2     3126        // 32-node sub-granules stored (3125 real + 1 pad)
#define NG2R    3125        // real 32-node granules (3125*32 = 100000 exactly)
#define NGT2    3328        // padded stride for tmaxT (= 13*256)
#define NTP     (NG2 * 2)   // padded tiles = 6252
#define SGPC    50          // sub-granules per chunk (64 chunks x 50 = 3200)
#define INV_TAU 50.0f
#define MARGIN  0.7f        // flag margin: need 0.553 (w=1e-12) + 2x f16-err bound
#define CUT     0.553f
#define LCAP    64          // flagged-granule list capacity (typ ~1-2 used)

typedef __fp16 half8  __attribute__((ext_vector_type(8)));
typedef __fp16 half2v __attribute__((ext_vector_type(2)));
typedef float  floatx4 __attribute__((ext_vector_type(4)));

union H8 { half8 v8; half2v v2[4]; };

typedef const __attribute__((address_space(1))) char* gptr_t;
typedef __attribute__((address_space(3))) char* sptr_t;

// order-preserving float -> uint encoding (for atomicMax)
__device__ __forceinline__ unsigned enc_f32(float f) {
    unsigned b = __float_as_uint(f);
    return (b & 0x80000000u) ? ~b : (b | 0x80000000u);
}
__device__ __forceinline__ float dec_f32(unsigned u) {
    unsigned b = (u & 0x80000000u) ? (u & 0x7FFFFFFFu) : ~u;
    return __uint_as_float(b);
}

// ---------------------------------------------------------------------------
// k_convB: B (f32) -> fragment-major f16 RTZ array, zero-padded to NTP tiles.
// Entry (t, ks, lane): node = 16t + (lane&15), dims d = (lane>>4)*8 + ks*32 ..+8
// Also initializes the me atomic slot (runs first on the stream).
// ---------------------------------------------------------------------------
__global__ __launch_bounds__(512)
void k_convB(const float* __restrict__ B, __fp16* __restrict__ Bh,
             unsigned* __restrict__ me_u)
{
    const int t    = (int)blockIdx.x;
    const int ks   = (int)threadIdx.x >> 6;
    const int lane = (int)threadIdx.x & 63;
    if (t == 0 && threadIdx.x == 0) me_u[0] = 0u;   // encodes very-negative float
    H8 h;
    if (t < NT) {
        const int node = t * 16 + (lane & 15);
        const int d0   = ((lane >> 4) << 3) + (ks << 5);
        const float* bp = B + (size_t)node * DIM + d0;
        float4 b0 = *reinterpret_cast<const float4*>(bp);
        float4 b1 = *reinterpret_cast<const float4*>(bp + 4);
        h.v2[0] = __builtin_amdgcn_cvt_pkrtz(b0.x, b0.y);
        h.v2[1] = __builtin_amdgcn_cvt_pkrtz(b0.z, b0.w);
        h.v2[2] = __builtin_amdgcn_cvt_pkrtz(b1.x, b1.y);
        h.v2[3] = __builtin_amdgcn_cvt_pkrtz(b1.z, b1.w);
    } else {
        h.v2[0] = __builtin_amdgcn_cvt_pkrtz(0.f, 0.f);
        h.v2[1] = h.v2[0]; h.v2[2] = h.v2[0]; h.v2[3] = h.v2[0];
    }
    *reinterpret_cast<half8*>(Bh + (((size_t)t * 8 + ks) * 64 + lane) * 8) = h.v8;
}

// ---------------------------------------------------------------------------
// k_pass1: approx max-GEMM with counted-vmcnt pipeline (T3/T4).
// Grid 512 = 64 chunks (XCD-pinned) x 8 rowblocks; 256 thr = 4 waves; wave
// owns 64 rows (af[4][8] in regs, ~228 VGPR, 2 waves/SIMD, 2 blocks/CU).
// LDS: 4 x 16KB buffers, staged 3 ahead via global_load_lds. Per SG:
// counted s_waitcnt vmcnt(8) (newest-8 outstanding = L(sg+2)x4 + S(sg-1)x4,
// so own loads for sg are guaranteed landed) + raw asm s_barrier with
// "memory" clobber (compiler fence + HW barrier, NO vmcnt/lgkmcnt drain --
// the drain was __syncthreads' ~2x stall).
// ROUND-14 BUG FIXED: buffer index must be RELATIVE, (sg - s0) & 3 -- the
// prologue stages into buffers 0,1,2 but s0 = chunk*50 is ≡2 (mod 4) for odd
// chunks, so absolute sg&3 read the wrong buffer on half the chunks.
// ---------------------------------------------------------------------------
__global__ __launch_bounds__(256, 2)
void k_pass1(const float* __restrict__ A, const __fp16* __restrict__ Bh,
             float* __restrict__ tmax2)
{
    __shared__ __fp16 lds[4][8192];    // 4 x 16 KB sub-granule buffers

    const int tid  = (int)threadIdx.x;
    const int w    = tid >> 6;         // wave 0..3
    const int lane = tid & 63;
    const int col  = lane & 15;
    const int kg   = lane >> 4;

    const int bid   = (int)blockIdx.x;
    const int chunk = (bid & 7) * 8 + ((bid >> 3) & 7);   // XCD-pinned chunks
    const int rb    = bid >> 6;                           // 0..7

    const int s0 = chunk * SGPC;
    if (s0 >= NG2) return;
    const int s1 = (s0 + SGPC < NG2) ? s0 + SGPC : NG2;
    const int wrow0 = rb * 256 + w * 64;

    // A fragments: 4 rowsets x 8 ks (f16 RTZ)
    H8 af[4][8];
#pragma unroll
    for (int rs = 0; rs < 4; ++rs) {
        const float* ap = A + (size_t)(wrow0 + rs * 16 + col) * DIM + (kg << 3);
#pragma unroll
        for (int ks = 0; ks < 8; ++ks) {
            float4 x0 = *reinterpret_cast<const float4*>(ap + (ks << 5));
            float4 x1 = *reinterpret_cast<const float4*>(ap + (ks << 5) + 4);
            af[rs][ks].v2[0] = __builtin_amdgcn_cvt_pkrtz(x0.x, x0.y);
            af[rs][ks].v2[1] = __builtin_amdgcn_cvt_pkrtz(x0.z, x0.w);
            af[rs][ks].v2[2] = __builtin_amdgcn_cvt_pkrtz(x1.x, x1.y);
            af[rs][ks].v2[3] = __builtin_amdgcn_cvt_pkrtz(x1.z, x1.w);
        }
    }

    // Stage one 16 KB sub-granule: wave w covers bytes [w*4K, +4K), 4 issues.
    auto STAGE = [&](int buf, int sg) {
        const char* src = (const char*)Bh + ((size_t)sg << 14) + (w << 12) + (lane << 4);
        char* dstb = (char*)&lds[buf][0] + (w << 12);
#pragma unroll
        for (int i = 0; i < 4; ++i)
            __builtin_amdgcn_global_load_lds((gptr_t)(src + (i << 10)),
                                             (sptr_t)(dstb + (i << 10)), 16, 0, 0);
    };

    // Prologue: stage 3 sub-granules ahead (relative buffers 0,1,2).
    STAGE(0, s0);
    if (s0 + 1 < s1) STAGE(1, s0 + 1);
    if (s0 + 2 < s1) STAGE(2, s0 + 2);

    for (int sg = s0; sg < s1; ++sg) {
        // Counted wait: guarantees this wave's 4 loads for sg have landed
        // (newest-8 kept in flight: L(sg+2)x4 + S(sg-1)x4).
        if (sg <= s1 - 3)      asm volatile("s_waitcnt vmcnt(8)" ::: "memory");
        else if (sg == s1 - 2) asm volatile("s_waitcnt vmcnt(4)" ::: "memory");
        else                   asm volatile("s_waitcnt vmcnt(0)" ::: "memory");
        asm volatile("s_barrier" ::: "memory");   // raw barrier: no drain
        if (sg + 3 < s1) STAGE((sg + 3 - s0) & 3, sg + 3);

        const __fp16* base = &lds[(sg - s0) & 3][0] + lane * 8;
        float tm[4] = { -INFINITY, -INFINITY, -INFINITY, -INFINITY };

        half8 bfA[8], bfB[8];
#pragma unroll
        for (int ks = 0; ks < 8; ++ks)          // preload tile 0 of this SG
            bfA[ks] = *reinterpret_cast<const half8*>(base + ks * 512);

        // tile 0: MFMAs with tile-1 reads interleaved per-ks
        {
            floatx4 acc[4];
#pragma unroll
            for (int rs = 0; rs < 4; ++rs) acc[rs] = (floatx4){0.f, 0.f, 0.f, 0.f};
#pragma unroll
            for (int ks = 0; ks < 8; ++ks) {
                bfB[ks] = *reinterpret_cast<const half8*>(base + 4096 + ks * 512);
                acc[0] = __builtin_amdgcn_mfma_f32_16x16x32_f16(bfA[ks], af[0][ks].v8, acc[0], 0, 0, 0);
                acc[1] = __builtin_amdgcn_mfma_f32_16x16x32_f16(bfA[ks], af[1][ks].v8, acc[1], 0, 0, 0);
                acc[2] = __builtin_amdgcn_mfma_f32_16x16x32_f16(bfA[ks], af[2][ks].v8, acc[2], 0, 0, 0);
                acc[3] = __builtin_amdgcn_mfma_f32_16x16x32_f16(bfA[ks], af[3][ks].v8, acc[3], 0, 0, 0);
            }
#pragma unroll
            for (int rs = 0; rs < 4; ++rs)
                tm[rs] = fmaxf(tm[rs], fmaxf(fmaxf(acc[rs][0], acc[rs][1]),
                                             fmaxf(acc[rs][2], acc[rs][3])));
        }
        // tile 1
        {
            floatx4 acc[4];
#pragma unroll
            for (int rs = 0; rs < 4; ++rs) acc[rs] = (floatx4){0.f, 0.f, 0.f, 0.f};
#pragma unroll
            for (int ks = 0; ks < 8; ++ks) {
                acc[0] = __builtin_amdgcn_mfma_f32_16x16x32_f16(bfB[ks], af[0][ks].v8, acc[0], 0, 0, 0);
                acc[1] = __builtin_amdgcn_mfma_f32_16x16x32_f16(bfB[ks], af[1][ks].v8, acc[1], 0, 0, 0);
                acc[2] = __builtin_amdgcn_mfma_f32_16x16x32_f16(bfB[ks], af[2][ks].v8, acc[2], 0, 0, 0);
                acc[3] = __builtin_amdgcn_mfma_f32_16x16x32_f16(bfB[ks], af[3][ks].v8, acc[3], 0, 0, 0);
            }
#pragma unroll
            for (int rs = 0; rs < 4; ++rs)
                tm[rs] = fmaxf(tm[rs], fmaxf(fmaxf(acc[rs][0], acc[rs][1]),
                                             fmaxf(acc[rs][2], acc[rs][3])));
        }

        // reduce across the 4 kg groups (nodes 4kg+j of each tile)
#pragma unroll
        for (int rs = 0; rs < 4; ++rs) {
            tm[rs] = fmaxf(tm[rs], __shfl_xor(tm[rs], 16));
            tm[rs] = fmaxf(tm[rs], __shfl_xor(tm[rs], 32));
        }
        if (kg == 0) {
#pragma unroll
            for (int rs = 0; rs < 4; ++rs)
                tmax2[(size_t)sg * NP + wrow0 + rs * 16 + col] = tm[rs];
        }
    }
}

// ---------------------------------------------------------------------------
// k_tr: LDS-tiled transpose tmax2[g2][row] -> tmaxT[row][g2] (NGT2=3328
// padded, -inf fill). Both global access patterns fully coalesced.
// ---------------------------------------------------------------------------
__global__ __launch_bounds__(256)
void k_tr(const float* __restrict__ tmax2, float* __restrict__ tmaxT)
{
    __shared__ float tile[64][65];
    const int t  = (int)threadIdx.x;
    const int g0 = (int)blockIdx.x * 64;
    const int r0 = (int)blockIdx.y * 64;
    const int a  = t & 63;
    const int b  = t >> 6;     // 0..3
#pragma unroll
    for (int it = 0; it < 16; ++it) {
        int gi = b + it * 4;
        int g  = g0 + gi;
        tile[gi][a] = (g < NG2) ? tmax2[(size_t)g * NP + r0 + a] : -INFINITY;
    }
    __syncthreads();
#pragma unroll
    for (int it = 0; it < 16; ++it) {
        int ri = b + it * 4;
        tmaxT[(size_t)(r0 + ri) * NGT2 + g0 + a] = tile[a][ri];
    }
}

// ---------------------------------------------------------------------------
// k_finish: one 256-thread block per row.
// 1) thread t reads its 13 contiguous 32-node-granule maxes; block max M.
// 2) deterministic parallel compaction of flagged granules (tmax > M-MARGIN,
//    ~1-2 per row) via wave prefix-sum -> sorted list.
// 3) per flagged granule (32 nodes): exact f32 sims — 8 threads/node, 32
//    dims each, ald8[8][36] staggered LDS; ordered online softmax + sparse
//    PV; l2norm(A + msg/l); evidence = m.
// All branches block-uniform; all summation orders deterministic.
// ---------------------------------------------------------------------------
__global__ __launch_bounds__(256)
void k_finish(const float* __restrict__ A, const float* __restrict__ B,
              const float* __restrict__ tmaxT, float* __restrict__ out,
              float* __restrict__ evidence, unsigned* __restrict__ me_u)
{
    __shared__ float ald8[8][36];   // A row, 32-dim chunk c at ald8[c] (staggered)
    __shared__ float sims[32];
    __shared__ float red[8];
    __shared__ int   list[LCAP];
    __shared__ int   wsum[4];

    const int t    = (int)threadIdx.x;
    const int row  = (int)blockIdx.x;
    const int lane = t & 63;
    const int wv   = t >> 6;

    const float av_own = A[(size_t)row * DIM + t];
    ald8[t >> 5][t & 31] = av_own;

    // 1) load 13 owned granule maxes, block max
    float v[13];
    const float* tr = tmaxT + (size_t)row * NGT2 + t * 13;
    float M = -INFINITY;
#pragma unroll
    for (int k = 0; k < 13; ++k) { v[k] = tr[k]; M = fmaxf(M, v[k]); }
#pragma unroll
    for (int o = 1; o < 64; o <<= 1) M = fmaxf(M, __shfl_xor(M, o));
    if (lane == 0) red[wv] = M;
    __syncthreads();
    M = fmaxf(fmaxf(red[0], red[1]), fmaxf(red[2], red[3]));

    // 2) flag + deterministic compaction (list sorted by granule id)
    const float thr = M - MARGIN;
    int cnt = 0; unsigned mask13 = 0u;
#pragma unroll
    for (int k = 0; k < 13; ++k)
        if (v[k] > thr && (t * 13 + k) < NG2R) { mask13 |= (1u << k); ++cnt; }
    int pre = cnt;
#pragma unroll
    for (int o = 1; o < 64; o <<= 1) {
        int x = __shfl_up(pre, o);
        if (lane >= o) pre += x;
    }
    if (lane == 63) wsum[wv] = pre;
    __syncthreads();
    int woff = 0;
    for (int i = 0; i < wv; ++i) woff += wsum[i];
    int pos = woff + pre - cnt;
    if (mask13) {
#pragma unroll
        for (int k = 0; k < 13; ++k)
            if (mask13 & (1u << k)) {
                if (pos < LCAP) list[pos] = t * 13 + k;
                ++pos;
            }
    }
    __syncthreads();
    int total = wsum[0] + wsum[1] + wsum[2] + wsum[3];
    if (total > LCAP) total = LCAP;

    // 3) exact recompute per flagged granule, ordered online softmax
    float m = -INFINITY, l = 0.f, msg = 0.f;
    const int n = t >> 3, q8 = t & 7;   // node-in-granule, 32-dim chunk

    for (int e = 0; e < total; ++e) {
        const int g  = list[e];
        const int n0 = g * 32;          // always 32 real nodes (g < 3125)
        {
            float s = 0.f;
            const float4* bp = reinterpret_cast<const float4*>(B + (size_t)(n0 + n) * DIM + q8 * 32);
            const float4* ap = reinterpret_cast<const float4*>(&ald8[q8][0]);
#pragma unroll
            for (int i = 0; i < 8; ++i) {
                float4 b4 = bp[i], a4 = ap[i];
                s += a4.x * b4.x + a4.y * b4.y + a4.z * b4.z + a4.w * b4.w;
            }
            s += __shfl_xor(s, 1);
            s += __shfl_xor(s, 2);
            s += __shfl_xor(s, 4);
            __syncthreads();               // prior granule's sims reads done
            if (q8 == 0) sims[n] = s;
            __syncthreads();
        }
        float gm = -INFINITY;
#pragma unroll
        for (int i = 0; i < 32; ++i) gm = fmaxf(gm, sims[i]);
        if (gm > m) {                       // block-uniform
            float sc = __expf((m - gm) * INV_TAU);
            m = gm; l *= sc; msg *= sc;
        }
        const float cut = m - CUT;
        for (int i = 0; i < 32; ++i) {      // ordered, deterministic
            float si = sims[i];
            if (si > cut) {
                float wn = __expf((si - m) * INV_TAU);
                l += wn;
                msg += wn * B[(size_t)(n0 + i) * DIM + t];
            }
        }
    }

    float u = av_own + msg * (1.0f / l);
    float ss = u * u;
#pragma unroll
    for (int o = 1; o < 64; o <<= 1) ss += __shfl_xor(ss, o);
    if (lane == 0) red[4 + wv] = ss;
    __syncthreads();
    ss = (red[4] + red[5]) + (red[6] + red[7]);
    float rn = 1.0f / fmaxf(sqrtf(ss), 1e-12f);
    out[256 + (size_t)row * DIM + t] = u * rn;
    if (t == 0) {
        evidence[row] = m;
        atomicMax(me_u, enc_f32(m));
    }
}

// ---------------------------------------------------------------------------
// k_gpart: partial evidence-weighted sums of `updated` (16 blocks x 128 rows).
// ---------------------------------------------------------------------------
__global__ __launch_bounds__(256)
void k_gpart(const float* __restrict__ evidence, const unsigned* __restrict__ me_u,
             const float* __restrict__ out, float* __restrict__ gpart)
{
    __shared__ float wsh[128];
    int tid = (int)threadIdx.x;
    int r0  = blockIdx.x * 128;
    float Me = dec_f32(me_u[0]);
    if (tid < 128) wsh[tid] = __expf((evidence[r0 + tid] - Me) * INV_TAU);
    __syncthreads();
    float g = 0.0f;
    for (int k = 0; k < 128; ++k)
        g += wsh[k] * out[256 + (size_t)(r0 + k) * DIM + tid];
    gpart[blockIdx.x * 256 + tid] = g;
}

// ---------------------------------------------------------------------------
// k_final: reduce partials, l2-normalize, write global feature to out[0..255].
// ---------------------------------------------------------------------------
__global__ __launch_bounds__(256)
void k_final(const float* __restrict__ gpart, float* __restrict__ out)
{
    __shared__ float red[256];
    int tid = (int)threadIdx.x;
    float g = 0.0f;
#pragma unroll
    for (int b = 0; b < 16; ++b) g += gpart[b * 256 + tid];
    red[tid] = g * g; __syncthreads();
    for (int s = 128; s > 0; s >>= 1) {
        if (tid < s) red[tid] += red[tid + s];
        __syncthreads();
    }
    float n = sqrtf(red[0]);
    float r = 1.0f / fmaxf(n, 1e-12f);
    out[tid] = g * r;
}

// ---------------------------------------------------------------------------
extern "C" void kernel_launch(void* const* d_in, const int* in_sizes, int n_in,
                              void* d_out, int out_size, void* d_ws, size_t ws_size,
                              hipStream_t stream)
{
    const float* A = (const float*)d_in[0];   // test_patches 2048x256 f32
    const float* B = (const float*)d_in[1];   // memory_nodes 100000x256 f32
    float* out = (float*)d_out;               // [256 global] + [2048x256 updated]
    float* ws  = (float*)d_ws;

    // ws layout (floats), with OVERLAY:
    //   region0: Bh (51.2 MB) during convB/pass1; reused as tmaxT (27.3 MB)
    //            from k_tr onward (Bh dead after pass1; same-stream ordering
    //            makes the overlay safe and replay-deterministic).
    //   tmax2  : NG2*NP floats (25.6 MB), layout [g2][row]
    //   evidence: 2048; me: 16; gpart: 4096
    __fp16* Bh      = (__fp16*)ws;
    float* tmaxT    = ws;                                  // overlay on Bh
    float* tmax2    = ws + (size_t)NTP * 2048;
    float* evidence = tmax2 + (size_t)NG2 * NP;
    unsigned* me_u  = (unsigned*)(evidence + NP);
    float* gpart    = (float*)(me_u + 16);

    k_convB <<<NTP,           512, 0, stream>>>(B, Bh, me_u);
    k_pass1 <<<512,           256, 0, stream>>>(A, Bh, tmax2);
    k_tr    <<<dim3(52, 32),  256, 0, stream>>>(tmax2, tmaxT);
    k_finish<<<NP,            256, 0, stream>>>(A, B, tmaxT, out, evidence, me_u);
    k_gpart <<<16,            256, 0, stream>>>(evidence, me_u, out, gpart);
    k_final <<<1,             256, 0, stream>>>(gpart, out);
}

// Round 16
// 181.509 us; speedup vs baseline: 1.0355x; 1.0355x over previous
//
#include <hip/hip_runtime.h>
#include <cstdint>
#include <cstddef>

// Problem constants
#define NP      2048        // patches
#define NN      100000      // memory nodes
#define DIM     256
#define NT      6250        // 16-node tiles (NN/16)
#define NG      1563        // 64-node granules = ceil(NT/4)
#define NG2     3126        // 32-node sub-granules stored (3125 real + 1 pad)
#define NG2R    3125        // real 32-node granules (3125*32 = 100000 exactly)
#define NGT2    3328        // padded stride for tmaxT (= 13*256)
#define NTP     (NG2 * 2)   // padded tiles = 6252
#define CPX     25          // 64-node granules per chunk (64 chunks x 25 = 1600)
#define INV_TAU 50.0f
#define MARGIN  0.7f        // flag margin: need 0.553 (w=1e-12) + 2x f16-err bound
#define CUT     0.553f
#define LCAP    64          // flagged-granule list capacity (typ ~1-2 used)

typedef __fp16 half8  __attribute__((ext_vector_type(8)));
typedef __fp16 half2v __attribute__((ext_vector_type(2)));
typedef float  floatx4 __attribute__((ext_vector_type(4)));

union H8 { half8 v8; half2v v2[4]; };

typedef const __attribute__((address_space(1))) char* gptr_t;
typedef __attribute__((address_space(3))) char* sptr_t;

// order-preserving float -> uint encoding (for atomicMax)
__device__ __forceinline__ unsigned enc_f32(float f) {
    unsigned b = __float_as_uint(f);
    return (b & 0x80000000u) ? ~b : (b | 0x80000000u);
}
__device__ __forceinline__ float dec_f32(unsigned u) {
    unsigned b = (u & 0x80000000u) ? (u & 0x7FFFFFFFu) : ~u;
    return __uint_as_float(b);
}

// ---------------------------------------------------------------------------
// k_convB: B (f32) -> fragment-major f16 RTZ array, zero-padded to NTP tiles.
// Entry (t, ks, lane): node = 16t + (lane&15), dims d = (lane>>4)*8 + ks*32 ..+8
// Also initializes the me atomic slot (runs first on the stream).
// ---------------------------------------------------------------------------
__global__ __launch_bounds__(512)
void k_convB(const float* __restrict__ B, __fp16* __restrict__ Bh,
             unsigned* __restrict__ me_u)
{
    const int t    = (int)blockIdx.x;
    const int ks   = (int)threadIdx.x >> 6;
    const int lane = (int)threadIdx.x & 63;
    if (t == 0 && threadIdx.x == 0) me_u[0] = 0u;   // encodes very-negative float
    H8 h;
    if (t < NT) {
        const int node = t * 16 + (lane & 15);
        const int d0   = ((lane >> 4) << 3) + (ks << 5);
        const float* bp = B + (size_t)node * DIM + d0;
        float4 b0 = *reinterpret_cast<const float4*>(bp);
        float4 b1 = *reinterpret_cast<const float4*>(bp + 4);
        h.v2[0] = __builtin_amdgcn_cvt_pkrtz(b0.x, b0.y);
        h.v2[1] = __builtin_amdgcn_cvt_pkrtz(b0.z, b0.w);
        h.v2[2] = __builtin_amdgcn_cvt_pkrtz(b1.x, b1.y);
        h.v2[3] = __builtin_amdgcn_cvt_pkrtz(b1.z, b1.w);
    } else {
        h.v2[0] = __builtin_amdgcn_cvt_pkrtz(0.f, 0.f);
        h.v2[1] = h.v2[0]; h.v2[2] = h.v2[0]; h.v2[3] = h.v2[0];
    }
    *reinterpret_cast<half8*>(Bh + (((size_t)t * 8 + ks) * 64 + lane) * 8) = h.v8;
}

// ---------------------------------------------------------------------------
// k_pass1: approx max-GEMM (best-known config: round-11 schedule + round-12
// 32-node tmax writes). Grid 512 = 64 chunks (XCD-pinned) x 8 rowblocks;
// 256 thr = 4 waves; wave owns 64 rows (af[4][8] in regs, ~228 VGPR+AGPR,
// 2 waves/SIMD, 2 independent blocks/CU whose barriers interleave).
// LDS: 2 x 32 KB granule buffers; single __syncthreads per 64-node granule
// (top-of-loop barrier also orders prior reads before the next STAGE).
// Separate LD/FM 2-deep phases (round-11's best: 100.5 us) with per-half
// max tracking for 32-node tmax2[g2][row] writes (finish granularity).
// Structural ceiling note: rounds 9-15 swept {bulk-LD, per-ks, 512/256-thr,
// counted-vmcnt, barrier-free}; all land 100-118 us at MfmaUtil 40-48% ==
// the plain-HIP 2-barrier GEMM ceiling (~950-1000 TF effective, m97-class).
// ---------------------------------------------------------------------------
__global__ __launch_bounds__(256, 2)
void k_pass1(const float* __restrict__ A, const __fp16* __restrict__ Bh,
             float* __restrict__ tmax2)
{
    __shared__ __fp16 lds[2][16384];   // 2 x 32 KB granule buffers

    const int tid  = (int)threadIdx.x;
    const int w    = tid >> 6;         // wave 0..3
    const int lane = tid & 63;
    const int col  = lane & 15;
    const int kg   = lane >> 4;

    const int bid   = (int)blockIdx.x;
    const int chunk = (bid & 7) * 8 + ((bid >> 3) & 7);   // XCD-pinned chunks
    const int rb    = bid >> 6;                           // 0..7

    const int g0 = chunk * CPX;
    if (g0 >= NG) return;
    const int g1 = (g0 + CPX < NG) ? g0 + CPX : NG;
    const int wrow0 = rb * 256 + w * 64;

    // A fragments: 4 rowsets x 8 ks (f16 RTZ)
    H8 af[4][8];
#pragma unroll
    for (int rs = 0; rs < 4; ++rs) {
        const float* ap = A + (size_t)(wrow0 + rs * 16 + col) * DIM + (kg << 3);
#pragma unroll
        for (int ks = 0; ks < 8; ++ks) {
            float4 x0 = *reinterpret_cast<const float4*>(ap + (ks << 5));
            float4 x1 = *reinterpret_cast<const float4*>(ap + (ks << 5) + 4);
            af[rs][ks].v2[0] = __builtin_amdgcn_cvt_pkrtz(x0.x, x0.y);
            af[rs][ks].v2[1] = __builtin_amdgcn_cvt_pkrtz(x0.z, x0.w);
            af[rs][ks].v2[2] = __builtin_amdgcn_cvt_pkrtz(x1.x, x1.y);
            af[rs][ks].v2[3] = __builtin_amdgcn_cvt_pkrtz(x1.z, x1.w);
        }
    }

    // Stage one 32 KB granule: wave w covers bytes [w*8K, w*8K+8K), 8 issues.
    auto STAGE = [&](int buf, int g) {
        const char* src = (const char*)Bh + ((size_t)g << 15) + (w << 13) + (lane << 4);
        char* dstb = (char*)&lds[buf][0] + (w << 13);
#pragma unroll
        for (int i = 0; i < 8; ++i)
            __builtin_amdgcn_global_load_lds((gptr_t)(src + (i << 10)),
                                             (sptr_t)(dstb + (i << 10)), 16, 0, 0);
    };

    STAGE(0, g0);
    int cur = 0;
    for (int g = g0; g < g1; ++g) {
        asm volatile("s_waitcnt vmcnt(0)" ::: "memory");
        __syncthreads();                       // buf[cur] staged for all waves;
                                               // also orders prior reads of
                                               // buf[cur^1] before next STAGE
        if (g + 1 < g1) STAGE(cur ^ 1, g + 1); // prefetch next granule

        const __fp16* base = &lds[cur][0] + lane * 8;
        float tmh[2][4];
#pragma unroll
        for (int hh = 0; hh < 2; ++hh)
#pragma unroll
            for (int rs = 0; rs < 4; ++rs) tmh[hh][rs] = -INFINITY;

        half8 bf0[8], bf1[8];
        auto LD = [&](half8 (&bf)[8], int tt) {
#pragma unroll
            for (int ks = 0; ks < 8; ++ks)
                bf[ks] = *reinterpret_cast<const half8*>(base + tt * 4096 + ks * 512);
        };
        auto FM = [&](const half8 (&bf)[8], int hh) {
            floatx4 acc[4];
#pragma unroll
            for (int rs = 0; rs < 4; ++rs) acc[rs] = (floatx4){0.f, 0.f, 0.f, 0.f};
#pragma unroll
            for (int ks = 0; ks < 8; ++ks) {
                acc[0] = __builtin_amdgcn_mfma_f32_16x16x32_f16(bf[ks], af[0][ks].v8, acc[0], 0, 0, 0);
                acc[1] = __builtin_amdgcn_mfma_f32_16x16x32_f16(bf[ks], af[1][ks].v8, acc[1], 0, 0, 0);
                acc[2] = __builtin_amdgcn_mfma_f32_16x16x32_f16(bf[ks], af[2][ks].v8, acc[2], 0, 0, 0);
                acc[3] = __builtin_amdgcn_mfma_f32_16x16x32_f16(bf[ks], af[3][ks].v8, acc[3], 0, 0, 0);
            }
#pragma unroll
            for (int rs = 0; rs < 4; ++rs)
                tmh[hh][rs] = fmaxf(tmh[hh][rs], fmaxf(fmaxf(acc[rs][0], acc[rs][1]),
                                                       fmaxf(acc[rs][2], acc[rs][3])));
        };

        // 2-deep software pipeline over the 4 tiles (round-11 schedule);
        // tiles 0-1 -> 32-node half 0, tiles 2-3 -> half 1.
        LD(bf0, 0);
        LD(bf1, 1);
        FM(bf0, 0);         // tile-1 reads in flight under tile-0 MFMAs
        LD(bf0, 2);
        FM(bf1, 0);
        LD(bf1, 3);
        FM(bf0, 1);
        FM(bf1, 1);

        // reduce across the 4 kg groups (nodes 4kg+j of each tile)
#pragma unroll
        for (int hh = 0; hh < 2; ++hh)
#pragma unroll
            for (int rs = 0; rs < 4; ++rs) {
                tmh[hh][rs] = fmaxf(tmh[hh][rs], __shfl_xor(tmh[hh][rs], 16));
                tmh[hh][rs] = fmaxf(tmh[hh][rs], __shfl_xor(tmh[hh][rs], 32));
            }
        if (kg == 0) {
#pragma unroll
            for (int hh = 0; hh < 2; ++hh)
#pragma unroll
                for (int rs = 0; rs < 4; ++rs)
                    tmax2[(size_t)(g * 2 + hh) * NP + wrow0 + rs * 16 + col] = tmh[hh][rs];
        }
        cur ^= 1;
    }
}

// ---------------------------------------------------------------------------
// k_tr: LDS-tiled transpose tmax2[g2][row] -> tmaxT[row][g2] (NGT2=3328
// padded, -inf fill). Both global access patterns fully coalesced.
// ---------------------------------------------------------------------------
__global__ __launch_bounds__(256)
void k_tr(const float* __restrict__ tmax2, float* __restrict__ tmaxT)
{
    __shared__ float tile[64][65];
    const int t  = (int)threadIdx.x;
    const int g0 = (int)blockIdx.x * 64;
    const int r0 = (int)blockIdx.y * 64;
    const int a  = t & 63;
    const int b  = t >> 6;     // 0..3
#pragma unroll
    for (int it = 0; it < 16; ++it) {
        int gi = b + it * 4;
        int g  = g0 + gi;
        tile[gi][a] = (g < NG2) ? tmax2[(size_t)g * NP + r0 + a] : -INFINITY;
    }
    __syncthreads();
#pragma unroll
    for (int it = 0; it < 16; ++it) {
        int ri = b + it * 4;
        tmaxT[(size_t)(r0 + ri) * NGT2 + g0 + a] = tile[a][ri];
    }
}

// ---------------------------------------------------------------------------
// k_finish: one 256-thread block per row.
// 1) thread t reads its 13 contiguous 32-node-granule maxes; block max M.
// 2) deterministic parallel compaction of flagged granules (tmax > M-MARGIN,
//    ~1-2 per row) via wave prefix-sum -> sorted list.
// 3) per flagged granule (32 nodes): exact f32 sims — 8 threads/node, 32
//    dims each, ald8[8][36] staggered LDS; ordered online softmax + sparse
//    PV; l2norm(A + msg/l); evidence = m.
// All branches block-uniform; all summation orders deterministic.
// ---------------------------------------------------------------------------
__global__ __launch_bounds__(256)
void k_finish(const float* __restrict__ A, const float* __restrict__ B,
              const float* __restrict__ tmaxT, float* __restrict__ out,
              float* __restrict__ evidence, unsigned* __restrict__ me_u)
{
    __shared__ float ald8[8][36];   // A row, 32-dim chunk c at ald8[c] (staggered)
    __shared__ float sims[32];
    __shared__ float red[8];
    __shared__ int   list[LCAP];
    __shared__ int   wsum[4];

    const int t    = (int)threadIdx.x;
    const int row  = (int)blockIdx.x;
    const int lane = t & 63;
    const int wv   = t >> 6;

    const float av_own = A[(size_t)row * DIM + t];
    ald8[t >> 5][t & 31] = av_own;

    // 1) load 13 owned granule maxes, block max
    float v[13];
    const float* tr = tmaxT + (size_t)row * NGT2 + t * 13;
    float M = -INFINITY;
#pragma unroll
    for (int k = 0; k < 13; ++k) { v[k] = tr[k]; M = fmaxf(M, v[k]); }
#pragma unroll
    for (int o = 1; o < 64; o <<= 1) M = fmaxf(M, __shfl_xor(M, o));
    if (lane == 0) red[wv] = M;
    __syncthreads();
    M = fmaxf(fmaxf(red[0], red[1]), fmaxf(red[2], red[3]));

    // 2) flag + deterministic compaction (list sorted by granule id)
    const float thr = M - MARGIN;
    int cnt = 0; unsigned mask13 = 0u;
#pragma unroll
    for (int k = 0; k < 13; ++k)
        if (v[k] > thr && (t * 13 + k) < NG2R) { mask13 |= (1u << k); ++cnt; }
    int pre = cnt;
#pragma unroll
    for (int o = 1; o < 64; o <<= 1) {
        int x = __shfl_up(pre, o);
        if (lane >= o) pre += x;
    }
    if (lane == 63) wsum[wv] = pre;
    __syncthreads();
    int woff = 0;
    for (int i = 0; i < wv; ++i) woff += wsum[i];
    int pos = woff + pre - cnt;
    if (mask13) {
#pragma unroll
        for (int k = 0; k < 13; ++k)
            if (mask13 & (1u << k)) {
                if (pos < LCAP) list[pos] = t * 13 + k;
                ++pos;
            }
    }
    __syncthreads();
    int total = wsum[0] + wsum[1] + wsum[2] + wsum[3];
    if (total > LCAP) total = LCAP;

    // 3) exact recompute per flagged granule, ordered online softmax
    float m = -INFINITY, l = 0.f, msg = 0.f;
    const int n = t >> 3, q8 = t & 7;   // node-in-granule, 32-dim chunk

    for (int e = 0; e < total; ++e) {
        const int g  = list[e];
        const int n0 = g * 32;          // always 32 real nodes (g < 3125)
        {
            float s = 0.f;
            const float4* bp = reinterpret_cast<const float4*>(B + (size_t)(n0 + n) * DIM + q8 * 32);
            const float4* ap = reinterpret_cast<const float4*>(&ald8[q8][0]);
#pragma unroll
            for (int i = 0; i < 8; ++i) {
                float4 b4 = bp[i], a4 = ap[i];
                s += a4.x * b4.x + a4.y * b4.y + a4.z * b4.z + a4.w * b4.w;
            }
            s += __shfl_xor(s, 1);
            s += __shfl_xor(s, 2);
            s += __shfl_xor(s, 4);
            __syncthreads();               // prior granule's sims reads done
            if (q8 == 0) sims[n] = s;
            __syncthreads();
        }
        float gm = -INFINITY;
#pragma unroll
        for (int i = 0; i < 32; ++i) gm = fmaxf(gm, sims[i]);
        if (gm > m) {                       // block-uniform
            float sc = __expf((m - gm) * INV_TAU);
            m = gm; l *= sc; msg *= sc;
        }
        const float cut = m - CUT;
        for (int i = 0; i < 32; ++i) {      // ordered, deterministic
            float si = sims[i];
            if (si > cut) {
                float wn = __expf((si - m) * INV_TAU);
                l += wn;
                msg += wn * B[(size_t)(n0 + i) * DIM + t];
            }
        }
    }

    float u = av_own + msg * (1.0f / l);
    float ss = u * u;
#pragma unroll
    for (int o = 1; o < 64; o <<= 1) ss += __shfl_xor(ss, o);
    if (lane == 0) red[4 + wv] = ss;
    __syncthreads();
    ss = (red[4] + red[5]) + (red[6] + red[7]);
    float rn = 1.0f / fmaxf(sqrtf(ss), 1e-12f);
    out[256 + (size_t)row * DIM + t] = u * rn;
    if (t == 0) {
        evidence[row] = m;
        atomicMax(me_u, enc_f32(m));
    }
}

// ---------------------------------------------------------------------------
// k_gpart: partial evidence-weighted sums of `updated` (16 blocks x 128 rows).
// ---------------------------------------------------------------------------
__global__ __launch_bounds__(256)
void k_gpart(const float* __restrict__ evidence, const unsigned* __restrict__ me_u,
             const float* __restrict__ out, float* __restrict__ gpart)
{
    __shared__ float wsh[128];
    int tid = (int)threadIdx.x;
    int r0  = blockIdx.x * 128;
    float Me = dec_f32(me_u[0]);
    if (tid < 128) wsh[tid] = __expf((evidence[r0 + tid] - Me) * INV_TAU);
    __syncthreads();
    float g = 0.0f;
    for (int k = 0; k < 128; ++k)
        g += wsh[k] * out[256 + (size_t)(r0 + k) * DIM + tid];
    gpart[blockIdx.x * 256 + tid] = g;
}

// ---------------------------------------------------------------------------
// k_final: reduce partials, l2-normalize, write global feature to out[0..255].
// ---------------------------------------------------------------------------
__global__ __launch_bounds__(256)
void k_final(const float* __restrict__ gpart, float* __restrict__ out)
{
    __shared__ float red[256];
    int tid = (int)threadIdx.x;
    float g = 0.0f;
#pragma unroll
    for (int b = 0; b < 16; ++b) g += gpart[b * 256 + tid];
    red[tid] = g * g; __syncthreads();
    for (int s = 128; s > 0; s >>= 1) {
        if (tid < s) red[tid] += red[tid + s];
        __syncthreads();
    }
    float n = sqrtf(red[0]);
    float r = 1.0f / fmaxf(n, 1e-12f);
    out[tid] = g * r;
}

// ---------------------------------------------------------------------------
extern "C" void kernel_launch(void* const* d_in, const int* in_sizes, int n_in,
                              void* d_out, int out_size, void* d_ws, size_t ws_size,
                              hipStream_t stream)
{
    const float* A = (const float*)d_in[0];   // test_patches 2048x256 f32
    const float* B = (const float*)d_in[1];   // memory_nodes 100000x256 f32
    float* out = (float*)d_out;               // [256 global] + [2048x256 updated]
    float* ws  = (float*)d_ws;

    // ws layout (floats), with OVERLAY:
    //   region0: Bh (51.2 MB) during convB/pass1; reused as tmaxT (27.3 MB)
    //            from k_tr onward (Bh dead after pass1; same-stream ordering
    //            makes the overlay safe and replay-deterministic).
    //   tmax2  : NG2*NP floats (25.6 MB), layout [g2][row]
    //   evidence: 2048; me: 16; gpart: 4096
    __fp16* Bh      = (__fp16*)ws;
    float* tmaxT    = ws;                                  // overlay on Bh
    float* tmax2    = ws + (size_t)NTP * 2048;
    float* evidence = tmax2 + (size_t)NG2 * NP;
    unsigned* me_u  = (unsigned*)(evidence + NP);
    float* gpart    = (float*)(me_u + 16);

    k_convB <<<NTP,           512, 0, stream>>>(B, Bh, me_u);
    k_pass1 <<<512,           256, 0, stream>>>(A, Bh, tmax2);
    k_tr    <<<dim3(52, 32),  256, 0, stream>>>(tmax2, tmaxT);
    k_finish<<<NP,            256, 0, stream>>>(A, B, tmaxT, out, evidence, me_u);
    k_gpart <<<16,            256, 0, stream>>>(evidence, me_u, out, gpart);
    k_final <<<1,             256, 0, stream>>>(gpart, out);
}